// Round 5
// baseline (95937.555 us; speedup 1.0000x reference)
//
#include <hip/hip_runtime.h>
#include <math.h>

// Problem constants
constexpr int Bb = 64, Tt = 500, Ee = 256, Aa = 128, Dd = 400;
constexpr int STEPS = 500, Rr = 5;

// d_ws layout (float offsets)
constexpr size_t WS_ENCPROJ_F = 0;                              // [64][500][128]
constexpr size_t WS_STAGE_F   = (size_t)Bb * Tt * Aa;           // [64][2048]
constexpr size_t WS_CNT_F     = WS_STAGE_F + (size_t)Bb * 2048; // [64][64] u32
constexpr int SG_H = 0, SG_STAT = 256, SG_CTXP = 512;
constexpr int SG_STRIDE = 2048;

// ---------------------------------------------------------------------------
// Pre-kernel: enc_proj[b,t,a] = sum_k enc_feat[b,t,k] * W_enc[k,a]
// ---------------------------------------------------------------------------
__global__ __launch_bounds__(512)
void k_encproj(const float* __restrict__ enc_feat,
               const float* __restrict__ W_enc,
               float* __restrict__ enc_proj) {
  __shared__ float sFeat[16][256];
  const int b = blockIdx.x, tg = blockIdx.y;
  const int t0 = tg * 16;
  const int tid = threadIdx.x;

  #pragma unroll
  for (int i = 0; i < 8; ++i) {
    int idx = tid + i * 512;
    int r = idx >> 8, c = idx & 255;
    int t = t0 + r;
    sFeat[r][c] = (t < Tt) ? enc_feat[((size_t)b * Tt + t) * Ee + c] : 0.0f;
  }
  __syncthreads();

  const int a = tid & 127, tl = tid >> 7;
  float acc0 = 0.f, acc1 = 0.f, acc2 = 0.f, acc3 = 0.f;
  #pragma unroll 4
  for (int k = 0; k < Ee; ++k) {
    float w = W_enc[k * Aa + a];
    acc0 = fmaf(sFeat[tl][k],      w, acc0);
    acc1 = fmaf(sFeat[tl + 4][k],  w, acc1);
    acc2 = fmaf(sFeat[tl + 8][k],  w, acc2);
    acc3 = fmaf(sFeat[tl + 12][k], w, acc3);
  }
  float accs[4] = {acc0, acc1, acc2, acc3};
  #pragma unroll
  for (int i = 0; i < 4; ++i) {
    int t = t0 + tl + 4 * i;
    if (t < Tt) enc_proj[((size_t)b * Tt + t) * Aa + a] = accs[i];
  }
}

// ---------------------------------------------------------------------------
// Helpers
// ---------------------------------------------------------------------------
// Deep-pipelined GEMV fragment: KS k-iterations, NB-deep double-buffered
// register loads (all NB loads issued before use; next batch issued while
// current batch is consumed). All indices compile-time (no scratch).
template<int KS, int NB>
__device__ __forceinline__ float4 dotq_db(const float* __restrict__ W, const int ldW,
                                          const float* __restrict__ x) {
  float4 acc = {0.f, 0.f, 0.f, 0.f};
  constexpr int NC = KS / NB;
  constexpr int TL = KS - NC * NB;
  float4 Abuf[NB], Bbuf[NB > 0 ? NB : 1];
  if constexpr (NC > 0) {
    #pragma unroll
    for (int j = 0; j < NB; ++j) Abuf[j] = *(const float4*)(W + (size_t)j * ldW);
  }
  #pragma unroll
  for (int c = 0; c < NC; ++c) {
    float4* cur = (c & 1) ? Bbuf : Abuf;
    float4* nxt = (c & 1) ? Abuf : Bbuf;
    if (c + 1 < NC) {
      const float* Wn = W + (size_t)((c + 1) * NB) * ldW;
      #pragma unroll
      for (int j = 0; j < NB; ++j) nxt[j] = *(const float4*)(Wn + (size_t)j * ldW);
    } else if constexpr (TL > 0) {
      const float* Wn = W + (size_t)(NC * NB) * ldW;
      #pragma unroll
      for (int j = 0; j < TL; ++j) nxt[j] = *(const float4*)(Wn + (size_t)j * ldW);
    }
    const float* xb = x + c * NB;
    #pragma unroll
    for (int j = 0; j < NB; ++j) {
      float xv = xb[j];
      acc.x = fmaf(xv, cur[j].x, acc.x); acc.y = fmaf(xv, cur[j].y, acc.y);
      acc.z = fmaf(xv, cur[j].z, acc.z); acc.w = fmaf(xv, cur[j].w, acc.w);
    }
  }
  if constexpr (TL > 0) {
    float4* cur = (NC & 1) ? Bbuf : Abuf;
    if constexpr (NC == 0) {
      #pragma unroll
      for (int j = 0; j < TL; ++j) cur[j] = *(const float4*)(W + (size_t)j * ldW);
    }
    const float* xb = x + NC * NB;
    #pragma unroll
    for (int j = 0; j < TL; ++j) {
      float xv = xb[j];
      acc.x = fmaf(xv, cur[j].x, acc.x); acc.y = fmaf(xv, cur[j].y, acc.y);
      acc.z = fmaf(xv, cur[j].z, acc.z); acc.w = fmaf(xv, cur[j].w, acc.w);
    }
  }
  return acc;
}

__device__ __forceinline__ float sigmoid_acc(float x) {
  float e = __expf(-x);
  return 1.0f / (1.0f + e);
}
__device__ __forceinline__ float tanh_acc(float x) {
  float cx = fminf(9.5f, fmaxf(-9.5f, x));
  float e = __expf(2.0f * cx);
  return (e - 1.0f) / (e + 1.0f);
}
__device__ __forceinline__ float tanh_fast(float x) {
  float cx = fminf(9.5f, fmaxf(-9.5f, x));
  float e = __expf(2.0f * cx);
  return (e - 1.0f) * __builtin_amdgcn_rcpf(e + 1.0f);
}

// Per-row 4-block sync (proven in R3): release add + relaxed spin + acquire.
__device__ __forceinline__ void rowsync(unsigned* __restrict__ cnt, int tid, int& target) {
  __syncthreads();
  target += 4;
  if (tid == 0) {
    __hip_atomic_fetch_add(cnt, 1u, __ATOMIC_RELEASE, __HIP_MEMORY_SCOPE_AGENT);
    while (__hip_atomic_load(cnt, __ATOMIC_RELAXED, __HIP_MEMORY_SCOPE_AGENT) < (unsigned)target) { }
    __threadfence();
  }
  __syncthreads();
}

// ---------------------------------------------------------------------------
// Persistent decoder: 256 blocks (4 per row) x 512 threads. 3 syncs/step.
// Replicated: P1, P2, P6, P10, P11. Split: GRU (h cols), P7 (tt), P9 (tt).
// ---------------------------------------------------------------------------
__global__ __launch_bounds__(512)
void k_decoder(const float* __restrict__ enc_feat,
               const float* __restrict__ enc_proj,
               float* __restrict__ stage, unsigned* __restrict__ cntbase,
               const float* __restrict__ W_p1, const float* __restrict__ b_p1,
               const float* __restrict__ W_p2, const float* __restrict__ b_p2,
               const float* __restrict__ W_ix, const float* __restrict__ W_ih,
               const float* __restrict__ b_ix, const float* __restrict__ b_ih,
               const float* __restrict__ W_dec, const float* __restrict__ b_attn,
               const float* __restrict__ v_attn,
               const float* __restrict__ W_out, const float* __restrict__ b_out,
               float* __restrict__ pred_out, float* __restrict__ attn_out) {
  __shared__ __align__(16) float sPred[400];
  __shared__ __align__(16) float sIn[384];    // [x(128) | ctx_prev(256)]
  __shared__ __align__(16) float sL1[256];
  __shared__ __align__(16) float sCat[512];   // [h(256) | ctx(256)]
  __shared__ __align__(16) float sSd[128];
  __shared__ __align__(16) float sScore[128]; // this block's 125 scores/attn
  __shared__ __align__(16) float sRaw[400];
  __shared__ __align__(16) float sTmp[2048];
  __shared__ float sRed[8];

  float* sH = sCat;

  const int bid = blockIdx.x;
  const int r = bid & 63, j = bid >> 6;     // 4 blocks of row r are 64 apart -> same XCD (%8)
  const int tid = threadIdx.x;
  const int lane = tid & 63, wid = tid >> 6;
  const int l4 = tid & 3;

  float* stg = stage + (size_t)r * SG_STRIDE;
  unsigned* cnt = cntbase + r * 64;
  int target = 0;

  // ---- init local state
  for (int i = tid; i < 400; i += 512) sPred[i] = 0.f;
  if (tid < 256) { sH[tid] = 0.f; sIn[128 + tid] = 0.f; }

  // ---- preload constants
  float4 vq[8];
  #pragma unroll
  for (int i = 0; i < 8; ++i) vq[i] = *(const float4*)(v_attn + 4 * (l4 + 4 * i));

  float bP1 = 0.f;
  if (tid < 256) bP1 = b_p1[tid];
  float bR = 0.f, bZ = 0.f, bIN = 0.f, bHN = 0.f;
  if (tid < 64) {
    int c = 64 * j + tid;
    bR  = b_ix[c]       + b_ih[c];
    bZ  = b_ix[256 + c] + b_ih[256 + c];
    bIN = b_ix[512 + c];
    bHN = b_ih[512 + c];
  }
  float bP2 = 0.f, bAt = 0.f;
  if (tid < 128) { bP2 = b_p2[tid]; bAt = b_attn[tid]; }
  float bOut = 0.f;
  if (tid < 400) bOut = b_out[tid];

  // ---- per-thread GEMV geometry (constant across steps)
  // P1 replicated: 64 quads x 8 slices, KS=50, K=400
  const float* p1W = W_p1 + 4 * (tid & 63) + (size_t)((tid >> 6) * 50) * 256;
  const float* p1x = sPred + (tid >> 6) * 50;
  // P2 replicated: 32 quads x 16 slices, KS=16, K=256
  const float* p2W = W_p2 + 4 * (tid & 31) + (size_t)((tid >> 5) * 16) * 128;
  const float* p2x = sL1 + (tid >> 5) * 16;
  // P6 replicated: same geometry on W_dec, x = h
  const float* p6W = W_dec + 4 * (tid & 31) + (size_t)((tid >> 5) * 16) * 128;
  const float* p6x = sH + (tid >> 5) * 16;
  // GRU split: 48 quads (192 gate cols for this block's 64 h-cols) x 10 slices, KS=64
  const float* gW = W_ix;
  const float* gx = sIn;
  const bool gAct = tid < 480;
  if (gAct) {
    int q = tid % 48, s = tid / 48;
    int col = 256 * (q >> 4) + 64 * j + 4 * (q & 15);
    if (s < 6) { gW = W_ix + (size_t)(64 * s) * 768 + col; gx = sIn + 64 * s; }
    else       { gW = W_ih + (size_t)(64 * (s - 6)) * 768 + col; gx = sH + 64 * (s - 6); }
  }
  // P10 replicated: 100 quads x 4 slices, KS=128, K=512 (400 active)
  const int q10 = tid % 100, s10 = tid / 100;
  const float* p10W = W_out + 4 * q10 + (size_t)(128 * s10) * 400;
  const float* p10x = sCat + 128 * s10;
  // P7 split: this block's 125 tt; 4 lanes per tt
  const int tt7 = tid >> 2;
  const float* ep7 = enc_proj + ((size_t)r * Tt + (125 * j + tt7)) * Aa;
  // P9 split by tt: 64 e-quads x 8 tt-slices over this block's 125 tt
  const int e9q = tid & 63, t9s = tid >> 6;
  const int t9a = t9s * 16;
  const float* fb9 = enc_feat + ((size_t)r * Tt + 125 * j + t9a) * Ee + 4 * e9q;

  __syncthreads();

  for (int t = 0; t < STEPS; ++t) {
    // ======== P1 (repl): l1 = relu(pred @ W_p1 + b_p1) ========
    { float4 a = dotq_db<50, 8>(p1W, 256, p1x); *(float4*)&sTmp[tid * 4] = a; }
    __syncthreads();
    if (tid < 256) {
      float v = bP1;
      #pragma unroll
      for (int s = 0; s < 8; ++s) v += sTmp[(64 * s + (tid >> 2)) * 4 + (tid & 3)];
      sL1[tid] = fmaxf(v, 0.f);
    }
    __syncthreads();

    // ======== P2 (repl): x = relu(l1 @ W_p2 + b_p2) -> sIn[0:128] ========
    { float4 a = dotq_db<16, 16>(p2W, 128, p2x); *(float4*)&sTmp[tid * 4] = a; }
    __syncthreads();
    if (tid < 128) {
      float v = bP2;
      #pragma unroll
      for (int s = 0; s < 16; ++s) v += sTmp[(32 * s + (tid >> 2)) * 4 + (tid & 3)];
      sIn[tid] = fmaxf(v, 0.f);
    }
    __syncthreads();

    // ======== GRU (split): gate cols for h[64j..64j+64) ========
    if (gAct) { float4 a = dotq_db<64, 8>(gW, 768, gx); *(float4*)&sTmp[tid * 4] = a; }
    __syncthreads();
    if (tid < 64) {
      const int cq = tid >> 2, ce = tid & 3;
      float cr = bR, cz = bZ, vin = bIN, vhn = bHN;
      #pragma unroll
      for (int s = 0; s < 10; ++s) {
        cr += sTmp[(48 * s +      cq) * 4 + ce];
        cz += sTmp[(48 * s + 16 + cq) * 4 + ce];
      }
      #pragma unroll
      for (int s = 0; s < 6; ++s) vin += sTmp[(48 * s + 32 + cq) * 4 + ce];
      #pragma unroll
      for (int s = 6; s < 10; ++s) vhn += sTmp[(48 * s + 32 + cq) * 4 + ce];
      float rg = sigmoid_acc(cr);
      float zg = sigmoid_acc(cz);
      float n  = tanh_acc(vin + rg * vhn);
      stg[SG_H + 64 * j + tid] = (1.f - zg) * n + zg * sH[64 * j + tid];
    }
    rowsync(cnt, tid, target);                 // ---- SYNC 1 (h)
    if (tid < 256) sH[tid] = stg[SG_H + tid];
    __syncthreads();

    // ======== P6 (repl): sd = h @ W_dec + b_attn ========
    { float4 a = dotq_db<16, 16>(p6W, 128, p6x); *(float4*)&sTmp[tid * 4] = a; }
    __syncthreads();
    if (tid < 128) {
      float v = bAt;
      #pragma unroll
      for (int s = 0; s < 16; ++s) v += sTmp[(32 * s + (tid >> 2)) * 4 + (tid & 3)];
      sSd[tid] = v;
    }
    __syncthreads();

    // ======== P7 (split): scores for this block's 125 tt ========
    {
      float4 sdq[8];
      #pragma unroll
      for (int i = 0; i < 8; ++i) sdq[i] = *(const float4*)(sSd + 4 * (l4 + 4 * i));
      float acc = 0.f;
      if (tt7 < 125) {
        #pragma unroll
        for (int i = 0; i < 8; ++i) {
          float4 e4 = ((const float4*)ep7)[l4 + 4 * i];
          acc = fmaf(vq[i].x, tanh_fast(e4.x + sdq[i].x), acc);
          acc = fmaf(vq[i].y, tanh_fast(e4.y + sdq[i].y), acc);
          acc = fmaf(vq[i].z, tanh_fast(e4.z + sdq[i].z), acc);
          acc = fmaf(vq[i].w, tanh_fast(e4.w + sdq[i].w), acc);
        }
      }
      acc += __shfl_xor(acc, 1);
      acc += __shfl_xor(acc, 2);
      if (l4 == 0 && tt7 < 125) sScore[tt7] = acc;
      __syncthreads();
    }

    // ======== local softmax stats over 125 scores; publish (m, S) ========
    {
      float val = (tid < 125) ? sScore[tid] : -3.0e38f;
      float lm = val;
      #pragma unroll
      for (int off = 32; off >= 1; off >>= 1) lm = fmaxf(lm, __shfl_xor(lm, off));
      if (lane == 0) sRed[wid] = lm;
      __syncthreads();
      float bm = sRed[0];
      #pragma unroll
      for (int w = 1; w < 8; ++w) bm = fmaxf(bm, sRed[w]);
      float e = (tid < 125) ? __expf(val - bm) : 0.f;
      float lS = e;
      #pragma unroll
      for (int off = 32; off >= 1; off >>= 1) lS += __shfl_xor(lS, off);
      __syncthreads();
      if (lane == 0) sRed[wid] = lS;
      __syncthreads();
      if (tid == 0) {
        float S = 0.f;
        #pragma unroll
        for (int w = 0; w < 8; ++w) S += sRed[w];
        stg[SG_STAT + 2 * j] = bm;
        stg[SG_STAT + 2 * j + 1] = S;
      }
      rowsync(cnt, tid, target);               // ---- SYNC 2 (softmax stats)
      float m0 = stg[SG_STAT + 0], S0 = stg[SG_STAT + 1];
      float m1 = stg[SG_STAT + 2], S1 = stg[SG_STAT + 3];
      float m2 = stg[SG_STAT + 4], S2 = stg[SG_STAT + 5];
      float m3 = stg[SG_STAT + 6], S3 = stg[SG_STAT + 7];
      float M = fmaxf(fmaxf(m0, m1), fmaxf(m2, m3));
      float Sg = S0 * __expf(m0 - M) + S1 * __expf(m1 - M) +
                 S2 * __expf(m2 - M) + S3 * __expf(m3 - M);
      if (tid < 125) {
        float attn = __expf(sScore[tid] - M) / Sg;
        sScore[tid] = attn;
        attn_out[((size_t)r * STEPS + t) * Tt + 125 * j + tid] = attn;
      }
      __syncthreads();
    }

    // ======== P9 (split by tt): partial ctx over this block's 125 tt ========
    {
      float4 part;
      if (t9s < 7) part = dotq_db<16, 16>(fb9, Ee, sScore + t9a);
      else         part = dotq_db<13, 13>(fb9, Ee, sScore + t9a);
      *(float4*)&sTmp[tid * 4] = part;
      __syncthreads();
      if (tid < 256) {
        float v = 0.f;
        #pragma unroll
        for (int s = 0; s < 8; ++s) v += sTmp[(64 * s + (tid >> 2)) * 4 + (tid & 3)];
        stg[SG_CTXP + 256 * j + tid] = v;
      }
      rowsync(cnt, tid, target);               // ---- SYNC 3 (ctx reduce)
      if (tid < 256) {
        float v = stg[SG_CTXP + tid] + stg[SG_CTXP + 256 + tid] +
                  stg[SG_CTXP + 512 + tid] + stg[SG_CTXP + 768 + tid];
        sIn[128 + tid] = v;
        sCat[256 + tid] = v;
      }
      __syncthreads();
    }

    // ======== P10 (repl): raw = [h,ctx] @ W_out + b_out ========
    if (tid < 400) { float4 a = dotq_db<128, 8>(p10W, 400, p10x); *(float4*)&sTmp[tid * 4] = a; }
    __syncthreads();
    if (tid < 400) {
      float v = bOut;
      #pragma unroll
      for (int s = 0; s < 4; ++s) v += sTmp[(100 * s + (tid >> 2)) * 4 + (tid & 3)];
      sRaw[tid] = v;
    }
    __syncthreads();

    // ======== P11 (repl): chunked softmax -> sPred; j==0 writes ========
    {
      if (wid < Rr) {
        int d0 = wid * 80 + lane;
        float v0 = sRaw[d0];
        float v1 = (lane < 16) ? sRaw[d0 + 64] : -3.0e38f;
        float m = fmaxf(v0, v1);
        #pragma unroll
        for (int off = 32; off >= 1; off >>= 1) m = fmaxf(m, __shfl_xor(m, off));
        float e0 = __expf(v0 - m);
        float e1 = (lane < 16) ? __expf(v1 - m) : 0.f;
        float s = e0 + e1;
        #pragma unroll
        for (int off = 32; off >= 1; off >>= 1) s += __shfl_xor(s, off);
        float inv = 1.0f / s;
        float p0 = e0 * inv;
        sPred[d0] = p0;
        if (j == 0) pred_out[((size_t)r * STEPS + t) * Dd + d0] = p0;
        if (lane < 16) {
          float p1 = e1 * inv;
          sPred[d0 + 64] = p1;
          if (j == 0) pred_out[((size_t)r * STEPS + t) * Dd + d0 + 64] = p1;
        }
      }
      __syncthreads();
    }
  }
}

// ---------------------------------------------------------------------------
extern "C" void kernel_launch(void* const* d_in, const int* in_sizes, int n_in,
                              void* d_out, int out_size, void* d_ws, size_t ws_size,
                              hipStream_t stream) {
  const float* enc_feat = (const float*)d_in[0];
  const float* W_p1  = (const float*)d_in[1];
  const float* b_p1  = (const float*)d_in[2];
  const float* W_p2  = (const float*)d_in[3];
  const float* b_p2  = (const float*)d_in[4];
  const float* W_ix  = (const float*)d_in[5];
  const float* W_ih  = (const float*)d_in[6];
  const float* b_ix  = (const float*)d_in[7];
  const float* b_ih  = (const float*)d_in[8];
  const float* W_dec = (const float*)d_in[9];
  const float* W_enc = (const float*)d_in[10];
  const float* b_attn= (const float*)d_in[11];
  const float* v_attn= (const float*)d_in[12];
  const float* W_out = (const float*)d_in[13];
  const float* b_out = (const float*)d_in[14];

  float* pred_out = (float*)d_out;                          // [64,500,400]
  float* attn_out = pred_out + (size_t)Bb * STEPS * Dd;     // [64,500,500]

  float* enc_proj = (float*)d_ws + WS_ENCPROJ_F;
  float* stage    = (float*)d_ws + WS_STAGE_F;
  unsigned* cnt   = (unsigned*)((float*)d_ws + WS_CNT_F);

  (void)hipMemsetAsync(cnt, 0, 64 * 64 * sizeof(unsigned), stream);
  k_encproj<<<dim3(Bb, 32), 512, 0, stream>>>(enc_feat, W_enc, enc_proj);

  void* args[] = {
    (void*)&enc_feat, (void*)&enc_proj, (void*)&stage, (void*)&cnt,
    (void*)&W_p1, (void*)&b_p1, (void*)&W_p2, (void*)&b_p2,
    (void*)&W_ix, (void*)&W_ih, (void*)&b_ix, (void*)&b_ih,
    (void*)&W_dec, (void*)&b_attn, (void*)&v_attn,
    (void*)&W_out, (void*)&b_out, (void*)&pred_out, (void*)&attn_out
  };
  (void)hipLaunchCooperativeKernel(reinterpret_cast<const void*>(k_decoder),
                                   dim3(4 * Bb), dim3(512), args, 0, stream);
}

// Round 6
// 89001.086 us; speedup vs baseline: 1.0779x; 1.0779x over previous
//
#include <hip/hip_runtime.h>
#include <math.h>

// Problem constants
constexpr int Bb = 64, Tt = 500, Ee = 256, Aa = 128, Dd = 400;
constexpr int STEPS = 500;

// ---------------- ws layout (float offsets) ----------------
constexpr size_t WS_ENCPROJ = 0;                       // [64][500][128] = 4,096,000
constexpr size_t WS_WT      = 4096000;                 // transposed weights 864,256
constexpr size_t WS_STAGE   = WS_WT + 864256;          // 8 groups x 16384
constexpr size_t WS_CNT     = WS_STAGE + 8 * 16384;    // 8192 u32 (32 KB)
// WT sub-offsets (floats)
constexpr int OT_P1  = 0;        // W_p1T  [256][400]
constexpr int OT_P2  = 102400;   // W_p2T  [128][256]
constexpr int OT_DEC = 135168;   // W_decT [128][256]
constexpr int OT_G   = 167936;   // W_gT   [768][640]  ([Wix k0:384 | Wih k0:256] per gate col)
constexpr int OT_OUT = 659456;   // W_outT [400][512]
// stage sub-offsets (floats, per group)
constexpr int SL1 = 0, SH = 2048, SCTXP = 4096, SRAW = 8192, SPRED = 11392, SSTAT = 14592;

// ---------------------------------------------------------------------------
// One-time: transpose weights into ws (output-indexed gather; runs once)
// ---------------------------------------------------------------------------
__global__ __launch_bounds__(512)
void k_transpose(const float* __restrict__ W_p1, const float* __restrict__ W_p2,
                 const float* __restrict__ W_dec, const float* __restrict__ W_ix,
                 const float* __restrict__ W_ih, const float* __restrict__ W_out,
                 float* __restrict__ WT) {
  int i = blockIdx.x * 512 + threadIdx.x;
  if (i < 102400) { int j = i / 400, k = i % 400; WT[OT_P1 + i] = W_p1[k * 256 + j]; return; }
  i -= 102400;
  if (i < 32768) { int j = i / 256, k = i % 256; WT[OT_P2 + i] = W_p2[k * 128 + j]; return; }
  i -= 32768;
  if (i < 32768) { int j = i / 256, k = i % 256; WT[OT_DEC + i] = W_dec[k * 128 + j]; return; }
  i -= 32768;
  if (i < 491520) {
    int gc = i / 640, k = i % 640;
    WT[OT_G + i] = (k < 384) ? W_ix[(size_t)k * 768 + gc] : W_ih[(size_t)(k - 384) * 768 + gc];
    return;
  }
  i -= 491520;
  if (i < 204800) { int j = i / 512, k = i % 512; WT[OT_OUT + i] = W_out[k * 400 + j]; }
}

// ---------------------------------------------------------------------------
// Pre-kernel: enc_proj[b,t,a] = sum_k enc_feat[b,t,k] * W_enc[k,a]
// ---------------------------------------------------------------------------
__global__ __launch_bounds__(512)
void k_encproj(const float* __restrict__ enc_feat,
               const float* __restrict__ W_enc,
               float* __restrict__ enc_proj) {
  __shared__ float sFeat[16][256];
  const int b = blockIdx.x, tg = blockIdx.y;
  const int t0 = tg * 16;
  const int tid = threadIdx.x;
  #pragma unroll
  for (int i = 0; i < 8; ++i) {
    int idx = tid + i * 512;
    int r = idx >> 8, c = idx & 255;
    int t = t0 + r;
    sFeat[r][c] = (t < Tt) ? enc_feat[((size_t)b * Tt + t) * Ee + c] : 0.0f;
  }
  __syncthreads();
  const int a = tid & 127, tl = tid >> 7;
  float acc0 = 0.f, acc1 = 0.f, acc2 = 0.f, acc3 = 0.f;
  #pragma unroll 4
  for (int k = 0; k < Ee; ++k) {
    float w = W_enc[k * Aa + a];
    acc0 = fmaf(sFeat[tl][k],      w, acc0);
    acc1 = fmaf(sFeat[tl + 4][k],  w, acc1);
    acc2 = fmaf(sFeat[tl + 8][k],  w, acc2);
    acc3 = fmaf(sFeat[tl + 12][k], w, acc3);
  }
  float accs[4] = {acc0, acc1, acc2, acc3};
  #pragma unroll
  for (int i = 0; i < 4; ++i) {
    int t = t0 + tl + 4 * i;
    if (t < Tt) enc_proj[((size_t)b * Tt + t) * Aa + a] = accs[i];
  }
}

// ---------------------------------------------------------------------------
// Math helpers
// ---------------------------------------------------------------------------
__device__ __forceinline__ float sigmoid_acc(float x) {
  float e = __expf(-x);
  return 1.0f / (1.0f + e);
}
__device__ __forceinline__ float tanh_acc(float x) {
  float cx = fminf(9.5f, fmaxf(-9.5f, x));
  float e = __expf(2.0f * cx);
  return (e - 1.0f) / (e + 1.0f);
}
__device__ __forceinline__ float tanh_fast(float x) {
  float cx = fminf(9.5f, fmaxf(-9.5f, x));
  float e = __expf(2.0f * cx);
  return (e - 1.0f) * __builtin_amdgcn_rcpf(e + 1.0f);
}

// Group sync: 16 blocks, slot-per-block (64B apart). Parallel release-stores,
// parallel spin on 16 slots by lanes 0..15. Same pattern class proven in R3.
__device__ __forceinline__ void gsync(unsigned* __restrict__ slots, int i16, int tid, unsigned ep) {
  __syncthreads();
  if (tid == 0)
    __hip_atomic_store(&slots[i16 * 16], ep, __ATOMIC_RELEASE, __HIP_MEMORY_SCOPE_AGENT);
  if (tid < 16)
    while (__hip_atomic_load(&slots[tid * 16], __ATOMIC_RELAXED, __HIP_MEMORY_SCOPE_AGENT) < ep) { }
  __threadfence();
  __syncthreads();
}

// Pair sync (softmax stats exchange between the two blocks of one row)
__device__ __forceinline__ void psync(unsigned* __restrict__ self, unsigned* __restrict__ peer,
                                      int tid, unsigned ep) {
  __syncthreads();
  if (tid == 0) {
    __hip_atomic_store(self, ep, __ATOMIC_RELEASE, __HIP_MEMORY_SCOPE_AGENT);
    while (__hip_atomic_load(peer, __ATOMIC_RELAXED, __HIP_MEMORY_SCOPE_AGENT) < ep) { }
  }
  __threadfence();
  __syncthreads();
}

// ---------------------------------------------------------------------------
// Persistent decoder: 128 blocks = 8 groups (g = bid&7 -> one XCD under %8
// round-robin) x 16 blocks. Each group owns 8 batch rows. Big weights
// col-split 16-way (exclusive slices); W_p2/W_dec replicated (L2-hot).
// 5 group syncs + 1 pair flag per step.
// ---------------------------------------------------------------------------
__global__ __launch_bounds__(512)
void k_decoder(const float* __restrict__ enc_feat,
               const float* __restrict__ enc_proj,
               const float* __restrict__ WT,
               float* __restrict__ stage, unsigned* __restrict__ cnt,
               const float* __restrict__ b_p1, const float* __restrict__ b_p2,
               const float* __restrict__ b_ix, const float* __restrict__ b_ih,
               const float* __restrict__ b_attn, const float* __restrict__ v_attn,
               const float* __restrict__ b_out,
               float* __restrict__ pred_out, float* __restrict__ attn_out) {
  // LDS (mirrored per block; [r][k] row-major for float4 k-reads)
  __shared__ __align__(16) float predL[3200];   // [8][400]
  __shared__ __align__(16) float inL[5120];     // [8][640] = x(0:128)|ctx(128:384)|h(384:640)
  __shared__ __align__(16) float l1L[2048];     // [8][256]
  __shared__ __align__(16) float sdL[128];
  __shared__ __align__(16) float rawL[3200];    // [8][400]
  __shared__ __align__(16) float scoreL[256];   // own 250 tt
  __shared__ __align__(16) float sTmp[2048];
  __shared__ float sRed[8];

  const int bid = blockIdx.x;
  const int g = bid & 7, i16 = bid >> 3;
  const int ri = i16 >> 1, hf = i16 & 1;          // row-in-group, tt-half
  const int rowg = 8 * g + ri;                    // global batch row for P7-P11
  const int tid = threadIdx.x;
  const int lane = tid & 63, wid = tid >> 6;
  const int l4 = tid & 3;

  float* stg = stage + (size_t)g * 16384;
  unsigned* cslot = cnt + g * 1024;
  unsigned* pfSelf = cnt + g * 1024 + 512 + (ri * 2 + hf) * 16;
  unsigned* pfPeer = cnt + g * 1024 + 512 + (ri * 2 + (hf ^ 1)) * 16;

  const float* WT_p1  = WT + OT_P1;
  const float* WT_p2  = WT + OT_P2;
  const float* WT_dec = WT + OT_DEC;
  const float* WT_g   = WT + OT_G;
  const float* WT_out = WT + OT_OUT;

  // ---- init LDS state (pred=0, x/ctx/h=0)
  for (int i = tid; i < 3200; i += 512) predL[i] = 0.f;
  for (int i = tid; i < 5120; i += 512) inL[i] = 0.f;

  // ---- constants in registers
  float4 vq[8];
  #pragma unroll
  for (int i = 0; i < 8; ++i) vq[i] = *(const float4*)(v_attn + 4 * (l4 + 4 * i));

  // P1 geometry: 16 cols x 8 rows x 4 k-slices (K=400)
  const int c1 = tid & 15, r1 = (tid >> 4) & 7, s1 = tid >> 7;
  const float* w1 = WT_p1 + (size_t)(16 * i16 + c1) * 400 + 100 * s1;
  const int xo1 = r1 * 400 + 100 * s1;
  float bP1 = 0.f;
  if (tid < 128) bP1 = b_p1[16 * i16 + (tid & 15)];

  // P2 geometry (replicated): 64 col-pairs x 8 rows, full K=256
  const int cp2 = tid >> 3, r2 = tid & 7;
  const float* w2a = WT_p2 + (size_t)(2 * cp2) * 256;
  const float* w2b = w2a + 256;
  const int xo2 = r2 * 256;
  const int dst2 = r2 * 640 + 2 * cp2;
  const float bP2a = b_p2[2 * cp2], bP2b = b_p2[2 * cp2 + 1];

  // GRU geometry: 24 col-pairs x 8 rows x 2 k-parts (384 active threads)
  const bool gAct = tid < 384;
  int gc0 = 0, gc1 = 0, sg = 0, rg = 0, sti0 = 0, sti1 = 0, xog = 0;
  if (gAct) {
    int c2 = tid % 24; rg = (tid / 24) & 7; sg = tid / 192;
    int lc0 = 2 * c2, lc1 = lc0 + 1;
    gc0 = (lc0 >> 4) * 256 + 16 * i16 + (lc0 & 15);
    gc1 = (lc1 >> 4) * 256 + 16 * i16 + (lc1 & 15);
    sti0 = sg * 384 + lc0 * 8 + rg;
    sti1 = sg * 384 + lc1 * 8 + rg;
    xog = rg * 640 + (sg ? 384 : 0);
  }
  const float* wg0 = WT_g + (size_t)gc0 * 640 + (sg ? 384 : 0);
  const float* wg1 = WT_g + (size_t)gc1 * 640 + (sg ? 384 : 0);
  // GRU combine (tid<128): 16 h-cols x 8 rows
  float bR = 0.f, bZ = 0.f, bIN = 0.f, bHN = 0.f;
  int colC = 0, rC = 0, holdOff = 0, stH = 0;
  if (tid < 128) {
    int hc = tid >> 3; rC = tid & 7; colC = 16 * i16 + hc;
    bR  = b_ix[colC]       + b_ih[colC];
    bZ  = b_ix[256 + colC] + b_ih[256 + colC];
    bIN = b_ix[512 + colC];
    bHN = b_ih[512 + colC];
    holdOff = rC * 640 + 384 + colC;
    stH = colC * 8 + rC;
  }

  // P6 geometry (per-block row ri): 128 cols x 4 k-slices (K=256)
  const int c6 = tid & 127, s6 = tid >> 7;
  const float* w6 = WT_dec + (size_t)c6 * 256 + 64 * s6;
  const int xo6 = ri * 640 + 384 + 64 * s6;
  float bAt = 0.f;
  if (tid < 128) bAt = b_attn[tid];

  // P7 pointers
  const float* encp = enc_proj + ((size_t)rowg * Tt + 250 * hf) * Aa;
  // P9 geometry: 64 e-quads x 8 tt-slices over own 250 tt
  const int e9q = tid & 63, sl9 = tid >> 6;
  const int t9a = sl9 * 32;
  const int t9b = (t9a + 32 < 250) ? t9a + 32 : 250;
  const float* encf = enc_feat + ((size_t)rowg * Tt + 250 * hf) * Ee + 4 * e9q;

  // P10 geometry: 25 cols x 8 rows x 2 k-halves (400 active)
  const bool a10 = tid < 400;
  int c25 = 0, r10 = 0, s10 = 0;
  if (a10) { c25 = tid % 25; r10 = (tid / 25) & 7; s10 = tid / 200; }
  const float* w10 = WT_out + (size_t)(25 * i16 + c25) * 512 + 256 * s10;
  const int xo10 = r10 * 640 + (s10 ? 128 : 384);   // k<256 -> h, k>=256 -> ctx
  float bO = 0.f;
  int stRAW = 0;
  if (tid < 200) {
    int cw = tid % 25, rw = tid / 25;
    bO = b_out[25 * i16 + cw];
    stRAW = (25 * i16 + cw) * 8 + rw;
  }

  // P11: row ri, chunks (hf==0: 0,1,2 ; hf==1: 3,4)
  const int nch = hf ? 2 : 3, ch0 = hf ? 3 : 0;

  __syncthreads();

  unsigned ep = 0;

  for (int t = 0; t < STEPS; ++t) {
    // ---- refill pred from stage (skip t=0: predL zero-initialized)
    if (t > 0) {
      {
        int i4 = tid;
        float4 v = *(const float4*)(stg + SPRED + 4 * i4);
        int col = (4 * i4) >> 3, rb = (4 * i4) & 7;
        predL[(rb + 0) * 400 + col] = v.x; predL[(rb + 1) * 400 + col] = v.y;
        predL[(rb + 2) * 400 + col] = v.z; predL[(rb + 3) * 400 + col] = v.w;
      }
      if (tid < 288) {
        int i4 = tid + 512;
        float4 v = *(const float4*)(stg + SPRED + 4 * i4);
        int col = (4 * i4) >> 3, rb = (4 * i4) & 7;
        predL[(rb + 0) * 400 + col] = v.x; predL[(rb + 1) * 400 + col] = v.y;
        predL[(rb + 2) * 400 + col] = v.z; predL[(rb + 3) * 400 + col] = v.w;
      }
      __syncthreads();
    }

    // ======== P1 (col-split): l1 cols [16*i16, +16) for all 8 rows ========
    {
      float acc = 0.f;
      #pragma unroll 5
      for (int k = 0; k < 100; k += 4) {
        float4 w4 = *(const float4*)(w1 + k);
        float4 x4 = *(const float4*)(predL + xo1 + k);
        acc = fmaf(w4.x, x4.x, acc); acc = fmaf(w4.y, x4.y, acc);
        acc = fmaf(w4.z, x4.z, acc); acc = fmaf(w4.w, x4.w, acc);
      }
      sTmp[tid] = acc;
    }
    __syncthreads();
    if (tid < 128) {
      float v = bP1 + sTmp[tid] + sTmp[tid + 128] + sTmp[tid + 256] + sTmp[tid + 384];
      stg[SL1 + (16 * i16 + (tid & 15)) * 8 + (tid >> 4)] = fmaxf(v, 0.f);
    }
    gsync(cslot, i16, tid, ++ep);                     // SYNC 1 (l1)

    // ---- refill l1 -> l1L [r][256]
    {
      int i4 = tid;
      float4 v = *(const float4*)(stg + SL1 + 4 * i4);
      int col = (4 * i4) >> 3, rb = (4 * i4) & 7;
      l1L[(rb + 0) * 256 + col] = v.x; l1L[(rb + 1) * 256 + col] = v.y;
      l1L[(rb + 2) * 256 + col] = v.z; l1L[(rb + 3) * 256 + col] = v.w;
    }
    __syncthreads();

    // ======== P2 (replicated): x = relu(l1 @ W_p2 + b) -> inL x-section ====
    {
      float a0 = 0.f, a1 = 0.f;
      #pragma unroll 8
      for (int k = 0; k < 256; k += 4) {
        float4 x4 = *(const float4*)(l1L + xo2 + k);
        float4 wA = *(const float4*)(w2a + k);
        float4 wB = *(const float4*)(w2b + k);
        a0 = fmaf(wA.x, x4.x, a0); a0 = fmaf(wA.y, x4.y, a0);
        a0 = fmaf(wA.z, x4.z, a0); a0 = fmaf(wA.w, x4.w, a0);
        a1 = fmaf(wB.x, x4.x, a1); a1 = fmaf(wB.y, x4.y, a1);
        a1 = fmaf(wB.z, x4.z, a1); a1 = fmaf(wB.w, x4.w, a1);
      }
      inL[dst2]     = fmaxf(a0 + bP2a, 0.f);
      inL[dst2 + 1] = fmaxf(a1 + bP2b, 0.f);
    }
    __syncthreads();

    // ======== GRU (col-split): 48 gate-cols (16 h-cols) x 8 rows ==========
    if (gAct) {
      float a0 = 0.f, a1 = 0.f;
      if (sg == 0) {
        #pragma unroll 8
        for (int k = 0; k < 384; k += 4) {
          float4 x4 = *(const float4*)(inL + xog + k);
          float4 wA = *(const float4*)(wg0 + k);
          float4 wB = *(const float4*)(wg1 + k);
          a0 = fmaf(wA.x, x4.x, a0); a0 = fmaf(wA.y, x4.y, a0);
          a0 = fmaf(wA.z, x4.z, a0); a0 = fmaf(wA.w, x4.w, a0);
          a1 = fmaf(wB.x, x4.x, a1); a1 = fmaf(wB.y, x4.y, a1);
          a1 = fmaf(wB.z, x4.z, a1); a1 = fmaf(wB.w, x4.w, a1);
        }
      } else {
        #pragma unroll 8
        for (int k = 0; k < 256; k += 4) {
          float4 x4 = *(const float4*)(inL + xog + k);
          float4 wA = *(const float4*)(wg0 + k);
          float4 wB = *(const float4*)(wg1 + k);
          a0 = fmaf(wA.x, x4.x, a0); a0 = fmaf(wA.y, x4.y, a0);
          a0 = fmaf(wA.z, x4.z, a0); a0 = fmaf(wA.w, x4.w, a0);
          a1 = fmaf(wB.x, x4.x, a1); a1 = fmaf(wB.y, x4.y, a1);
          a1 = fmaf(wB.z, x4.z, a1); a1 = fmaf(wB.w, x4.w, a1);
        }
      }
      sTmp[sti0] = a0;
      sTmp[sti1] = a1;
    }
    __syncthreads();
    if (tid < 128) {
      int hc = tid >> 3;
      float rpre = bR  + sTmp[hc * 8 + rC]        + sTmp[384 + hc * 8 + rC];
      float zpre = bZ  + sTmp[(16 + hc) * 8 + rC] + sTmp[384 + (16 + hc) * 8 + rC];
      float inp  = bIN + sTmp[(32 + hc) * 8 + rC];
      float hnp  = bHN + sTmp[384 + (32 + hc) * 8 + rC];
      float rgt = sigmoid_acc(rpre);
      float zgt = sigmoid_acc(zpre);
      float n   = tanh_acc(inp + rgt * hnp);
      stg[SH + stH] = (1.f - zgt) * n + zgt * inL[holdOff];
    }
    gsync(cslot, i16, tid, ++ep);                     // SYNC 2 (h)

    // ---- refill h -> inL h-section
    {
      int i4 = tid;
      float4 v = *(const float4*)(stg + SH + 4 * i4);
      int col = (4 * i4) >> 3, rb = (4 * i4) & 7;
      inL[(rb + 0) * 640 + 384 + col] = v.x; inL[(rb + 1) * 640 + 384 + col] = v.y;
      inL[(rb + 2) * 640 + 384 + col] = v.z; inL[(rb + 3) * 640 + 384 + col] = v.w;
    }
    __syncthreads();

    // ======== P6 (per-block row): sd = h[ri] @ W_dec + b_attn ============
    {
      float acc = 0.f;
      #pragma unroll 8
      for (int k = 0; k < 64; k += 4) {
        float4 w4 = *(const float4*)(w6 + k);
        float4 x4 = *(const float4*)(inL + xo6 + k);
        acc = fmaf(w4.x, x4.x, acc); acc = fmaf(w4.y, x4.y, acc);
        acc = fmaf(w4.z, x4.z, acc); acc = fmaf(w4.w, x4.w, acc);
      }
      sTmp[s6 * 128 + c6] = acc;
    }
    __syncthreads();
    if (tid < 128)
      sdL[tid] = bAt + sTmp[tid] + sTmp[128 + tid] + sTmp[256 + tid] + sTmp[384 + tid];
    __syncthreads();

    // ======== P7 (row-half): scores for own 250 tt ========================
    {
      float4 sdq[8];
      #pragma unroll
      for (int i = 0; i < 8; ++i) sdq[i] = *(const float4*)(sdL + 4 * (l4 + 4 * i));
      if (tid < 500) {
        #pragma unroll
        for (int p = 0; p < 2; ++p) {
          int ttl = p * 125 + (tid >> 2);
          const float* epn = encp + (size_t)ttl * 128 + 4 * l4;
          float acc = 0.f;
          #pragma unroll
          for (int i = 0; i < 8; ++i) {
            float4 e4 = *(const float4*)(epn + 16 * i);
            acc = fmaf(vq[i].x, tanh_fast(e4.x + sdq[i].x), acc);
            acc = fmaf(vq[i].y, tanh_fast(e4.y + sdq[i].y), acc);
            acc = fmaf(vq[i].z, tanh_fast(e4.z + sdq[i].z), acc);
            acc = fmaf(vq[i].w, tanh_fast(e4.w + sdq[i].w), acc);
          }
          acc += __shfl_xor(acc, 1);
          acc += __shfl_xor(acc, 2);
          if (l4 == 0) scoreL[ttl] = acc;
        }
      }
    }
    __syncthreads();

    // ======== P8: local stats, pair merge, attn ===========================
    {
      float val = (tid < 250) ? scoreL[tid] : -3.0e38f;
      float m = val;
      #pragma unroll
      for (int off = 32; off >= 1; off >>= 1) m = fmaxf(m, __shfl_xor(m, off));
      if (lane == 0) sRed[wid] = m;
      __syncthreads();
      float bm = sRed[0];
      #pragma unroll
      for (int w = 1; w < 8; ++w) bm = fmaxf(bm, sRed[w]);
      float e = (tid < 250) ? __expf(val - bm) : 0.f;
      float lS = e;
      #pragma unroll
      for (int off = 32; off >= 1; off >>= 1) lS += __shfl_xor(lS, off);
      __syncthreads();
      if (lane == 0) sRed[wid] = lS;
      __syncthreads();
      if (tid == 0) {
        float S = 0.f;
        #pragma unroll
        for (int w = 0; w < 8; ++w) S += sRed[w];
        stg[SSTAT + (ri * 2 + hf) * 2]     = bm;
        stg[SSTAT + (ri * 2 + hf) * 2 + 1] = S;
      }
      psync(pfSelf, pfPeer, tid, (unsigned)(t + 1));  // pair flag
      float m2 = stg[SSTAT + (ri * 2 + (hf ^ 1)) * 2];
      float S2 = stg[SSTAT + (ri * 2 + (hf ^ 1)) * 2 + 1];
      float S1v = stg[SSTAT + (ri * 2 + hf) * 2 + 1];
      float M = fmaxf(bm, m2);
      float Sg = S1v * __expf(bm - M) + S2 * __expf(m2 - M);
      if (tid < 250) {
        float attn = __expf(val - M) / Sg;
        scoreL[tid] = attn;
        attn_out[((size_t)rowg * STEPS + t) * Tt + 250 * hf + tid] = attn;
      }
    }
    __syncthreads();

    // ======== P9 (row-half): partial ctx over own 250 tt ==================
    {
      float4 acc = {0.f, 0.f, 0.f, 0.f};
      const float* fb = encf + (size_t)t9a * 256;
      for (int tt = t9a; tt < t9b; ++tt) {
        float a = scoreL[tt];
        float4 f = *(const float4*)fb;
        fb += 256;
        acc.x = fmaf(a, f.x, acc.x); acc.y = fmaf(a, f.y, acc.y);
        acc.z = fmaf(a, f.z, acc.z); acc.w = fmaf(a, f.w, acc.w);
      }
      *(float4*)&sTmp[tid * 4] = acc;
    }
    __syncthreads();
    if (tid < 64) {
      float4 v = {0.f, 0.f, 0.f, 0.f};
      #pragma unroll
      for (int s = 0; s < 8; ++s) {
        float4 u = *(const float4*)&sTmp[(s * 64 + tid) * 4];
        v.x += u.x; v.y += u.y; v.z += u.z; v.w += u.w;
      }
      *(float4*)&stg[SCTXP + hf * 2048 + ri * 256 + 4 * tid] = v;
    }
    gsync(cslot, i16, tid, ++ep);                     // SYNC 3 (ctx partials)

    // ---- refill ctx (merge halves) -> inL ctx-section
    {
      int rr = tid >> 6, e4 = (tid & 63) * 4;
      float4 a = *(const float4*)(stg + SCTXP + rr * 256 + e4);
      float4 b = *(const float4*)(stg + SCTXP + 2048 + rr * 256 + e4);
      float4 v = {a.x + b.x, a.y + b.y, a.z + b.z, a.w + b.w};
      *(float4*)(inL + rr * 640 + 128 + e4) = v;
    }
    __syncthreads();

    // ======== P10 (col-split): raw cols [25*i16,+25) for all 8 rows =======
    if (a10) {
      float acc = 0.f;
      #pragma unroll 8
      for (int k = 0; k < 256; k += 4) {
        float4 w4 = *(const float4*)(w10 + k);
        float4 x4 = *(const float4*)(inL + xo10 + k);
        acc = fmaf(w4.x, x4.x, acc); acc = fmaf(w4.y, x4.y, acc);
        acc = fmaf(w4.z, x4.z, acc); acc = fmaf(w4.w, x4.w, acc);
      }
      sTmp[tid] = acc;
    }
    __syncthreads();
    if (tid < 200)
      stg[SRAW + stRAW] = bO + sTmp[tid] + sTmp[tid + 200];
    gsync(cslot, i16, tid, ++ep);                     // SYNC 4 (raw)

    // ---- refill raw -> rawL [r][400]
    {
      int i4 = tid;
      float4 v = *(const float4*)(stg + SRAW + 4 * i4);
      int col = (4 * i4) >> 3, rb = (4 * i4) & 7;
      rawL[(rb + 0) * 400 + col] = v.x; rawL[(rb + 1) * 400 + col] = v.y;
      rawL[(rb + 2) * 400 + col] = v.z; rawL[(rb + 3) * 400 + col] = v.w;
    }
    if (tid < 288) {
      int i4 = tid + 512;
      float4 v = *(const float4*)(stg + SRAW + 4 * i4);
      int col = (4 * i4) >> 3, rb = (4 * i4) & 7;
      rawL[(rb + 0) * 400 + col] = v.x; rawL[(rb + 1) * 400 + col] = v.y;
      rawL[(rb + 2) * 400 + col] = v.z; rawL[(rb + 3) * 400 + col] = v.w;
    }
    __syncthreads();

    // ======== P11 (row-chunks): chunked softmax -> stage pred + pred_out ==
    if (wid < nch) {
      int ch = ch0 + wid;
      int d0 = ch * 80 + lane;
      float v0 = rawL[ri * 400 + d0];
      float v1 = (lane < 16) ? rawL[ri * 400 + d0 + 64] : -3.0e38f;
      float m = fmaxf(v0, v1);
      #pragma unroll
      for (int off = 32; off >= 1; off >>= 1) m = fmaxf(m, __shfl_xor(m, off));
      float e0 = __expf(v0 - m);
      float e1 = (lane < 16) ? __expf(v1 - m) : 0.f;
      float s = e0 + e1;
      #pragma unroll
      for (int off = 32; off >= 1; off >>= 1) s += __shfl_xor(s, off);
      float inv = 1.0f / s;
      float p0 = e0 * inv;
      stg[SPRED + d0 * 8 + ri] = p0;
      pred_out[((size_t)rowg * STEPS + t) * Dd + d0] = p0;
      if (lane < 16) {
        float p1 = e1 * inv;
        stg[SPRED + (d0 + 64) * 8 + ri] = p1;
        pred_out[((size_t)rowg * STEPS + t) * Dd + d0 + 64] = p1;
      }
    }
    gsync(cslot, i16, tid, ++ep);                     // SYNC 5 (pred)
  }
}

// ---------------------------------------------------------------------------
extern "C" void kernel_launch(void* const* d_in, const int* in_sizes, int n_in,
                              void* d_out, int out_size, void* d_ws, size_t ws_size,
                              hipStream_t stream) {
  const float* enc_feat = (const float*)d_in[0];
  const float* W_p1  = (const float*)d_in[1];
  const float* b_p1  = (const float*)d_in[2];
  const float* W_p2  = (const float*)d_in[3];
  const float* b_p2  = (const float*)d_in[4];
  const float* W_ix  = (const float*)d_in[5];
  const float* W_ih  = (const float*)d_in[6];
  const float* b_ix  = (const float*)d_in[7];
  const float* b_ih  = (const float*)d_in[8];
  const float* W_dec = (const float*)d_in[9];
  const float* W_enc = (const float*)d_in[10];
  const float* b_attn= (const float*)d_in[11];
  const float* v_attn= (const float*)d_in[12];
  const float* W_out = (const float*)d_in[13];
  const float* b_out = (const float*)d_in[14];

  float* pred_out = (float*)d_out;                          // [64,500,400]
  float* attn_out = pred_out + (size_t)Bb * STEPS * Dd;     // [64,500,500]

  float* ws = (float*)d_ws;
  float* enc_proj = ws + WS_ENCPROJ;
  float* WT       = ws + WS_WT;
  float* stage    = ws + WS_STAGE;
  unsigned* cnt   = (unsigned*)(ws + WS_CNT);

  (void)hipMemsetAsync(cnt, 0, 8192 * sizeof(unsigned), stream);
  k_transpose<<<1688, 512, 0, stream>>>(W_p1, W_p2, W_dec, W_ix, W_ih, W_out, WT);
  k_encproj<<<dim3(Bb, 32), 512, 0, stream>>>(enc_feat, W_enc, enc_proj);

  void* args[] = {
    (void*)&enc_feat, (void*)&enc_proj, (void*)&WT, (void*)&stage, (void*)&cnt,
    (void*)&b_p1, (void*)&b_p2, (void*)&b_ix, (void*)&b_ih,
    (void*)&b_attn, (void*)&v_attn, (void*)&b_out,
    (void*)&pred_out, (void*)&attn_out
  };
  (void)hipLaunchCooperativeKernel(reinterpret_cast<const void*>(k_decoder),
                                   dim3(128), dim3(512), args, 0, stream);
}

// Round 7
// 80735.779 us; speedup vs baseline: 1.1883x; 1.1024x over previous
//
#include <hip/hip_runtime.h>
#include <math.h>

// Problem constants
constexpr int Bb = 64, Tt = 500, Ee = 256, Aa = 128, Dd = 400;
constexpr int STEPS = 500, Rr = 5;

typedef float f4v __attribute__((ext_vector_type(4)));
__device__ __forceinline__ f4v ntl4(const float* p) {
  return __builtin_nontemporal_load((const f4v*)p);   // stream, don't cache in L2
}

// ---------------------------------------------------------------------------
// Pre-kernel: enc_proj[b,t,a] = sum_k enc_feat[b,t,k] * W_enc[k,a]
// ---------------------------------------------------------------------------
__global__ __launch_bounds__(512)
void k_encproj(const float* __restrict__ enc_feat,
               const float* __restrict__ W_enc,
               float* __restrict__ enc_proj) {
  __shared__ float sFeat[16][256];
  const int b = blockIdx.x, tg = blockIdx.y;
  const int t0 = tg * 16;
  const int tid = threadIdx.x;

  #pragma unroll
  for (int i = 0; i < 8; ++i) {
    int idx = tid + i * 512;
    int r = idx >> 8, c = idx & 255;
    int t = t0 + r;
    sFeat[r][c] = (t < Tt) ? enc_feat[((size_t)b * Tt + t) * Ee + c] : 0.0f;
  }
  __syncthreads();

  const int a = tid & 127, tl = tid >> 7;
  float acc0 = 0.f, acc1 = 0.f, acc2 = 0.f, acc3 = 0.f;
  #pragma unroll 4
  for (int k = 0; k < Ee; ++k) {
    float w = W_enc[k * Aa + a];
    acc0 = fmaf(sFeat[tl][k],      w, acc0);
    acc1 = fmaf(sFeat[tl + 4][k],  w, acc1);
    acc2 = fmaf(sFeat[tl + 8][k],  w, acc2);
    acc3 = fmaf(sFeat[tl + 12][k], w, acc3);
  }
  float accs[4] = {acc0, acc1, acc2, acc3};
  #pragma unroll
  for (int i = 0; i < 4; ++i) {
    int t = t0 + tl + 4 * i;
    if (t < Tt) enc_proj[((size_t)b * Tt + t) * Aa + a] = accs[i];
  }
}

// ---------------------------------------------------------------------------
// Deep-pipelined GEMV fragment (proven in R5): KS k-iters, NB-deep
// double-buffered register loads. All indices compile-time.
// ---------------------------------------------------------------------------
template<int KS, int NB>
__device__ __forceinline__ float4 dotq_db(const float* __restrict__ W, const int ldW,
                                          const float* __restrict__ x) {
  float4 acc = {0.f, 0.f, 0.f, 0.f};
  constexpr int NC = KS / NB;
  constexpr int TL = KS - NC * NB;
  float4 Abuf[NB], Bbuf[NB > 0 ? NB : 1];
  if constexpr (NC > 0) {
    #pragma unroll
    for (int j = 0; j < NB; ++j) Abuf[j] = *(const float4*)(W + (size_t)j * ldW);
  }
  #pragma unroll
  for (int c = 0; c < NC; ++c) {
    float4* cur = (c & 1) ? Bbuf : Abuf;
    float4* nxt = (c & 1) ? Abuf : Bbuf;
    if (c + 1 < NC) {
      const float* Wn = W + (size_t)((c + 1) * NB) * ldW;
      #pragma unroll
      for (int j = 0; j < NB; ++j) nxt[j] = *(const float4*)(Wn + (size_t)j * ldW);
    } else if constexpr (TL > 0) {
      const float* Wn = W + (size_t)(NC * NB) * ldW;
      #pragma unroll
      for (int j = 0; j < TL; ++j) nxt[j] = *(const float4*)(Wn + (size_t)j * ldW);
    }
    const float* xb = x + c * NB;
    #pragma unroll
    for (int j = 0; j < NB; ++j) {
      float xv = xb[j];
      acc.x = fmaf(xv, cur[j].x, acc.x); acc.y = fmaf(xv, cur[j].y, acc.y);
      acc.z = fmaf(xv, cur[j].z, acc.z); acc.w = fmaf(xv, cur[j].w, acc.w);
    }
  }
  if constexpr (TL > 0) {
    float4* cur = (NC & 1) ? Bbuf : Abuf;
    if constexpr (NC == 0) {
      #pragma unroll
      for (int j = 0; j < TL; ++j) cur[j] = *(const float4*)(W + (size_t)j * ldW);
    }
    const float* xb = x + NC * NB;
    #pragma unroll
    for (int j = 0; j < TL; ++j) {
      float xv = xb[j];
      acc.x = fmaf(xv, cur[j].x, acc.x); acc.y = fmaf(xv, cur[j].y, acc.y);
      acc.z = fmaf(xv, cur[j].z, acc.z); acc.w = fmaf(xv, cur[j].w, acc.w);
    }
  }
  return acc;
}

__device__ __forceinline__ float sigmoid_acc(float x) {
  float e = __expf(-x);
  return 1.0f / (1.0f + e);
}
__device__ __forceinline__ float tanh_acc(float x) {
  float cx = fminf(9.5f, fmaxf(-9.5f, x));
  float e = __expf(2.0f * cx);
  return (e - 1.0f) / (e + 1.0f);
}
__device__ __forceinline__ float tanh_fast(float x) {
  float cx = fminf(9.5f, fmaxf(-9.5f, x));
  float e = __expf(2.0f * cx);
  return (e - 1.0f) * __builtin_amdgcn_rcpf(e + 1.0f);
}

// ---------------------------------------------------------------------------
// Persistent decoder: 64 blocks x 1024 threads, state in LDS, no cross-block
// sync. launch_bounds(1024,4): 16 waves/CU at <=128 VGPR.
// ---------------------------------------------------------------------------
__global__ __launch_bounds__(1024, 4)
void k_decoder(const float* __restrict__ enc_feat,
               const float* __restrict__ enc_proj,
               const float* __restrict__ W_p1, const float* __restrict__ b_p1,
               const float* __restrict__ W_p2, const float* __restrict__ b_p2,
               const float* __restrict__ W_ix, const float* __restrict__ W_ih,
               const float* __restrict__ b_ix, const float* __restrict__ b_ih,
               const float* __restrict__ W_dec, const float* __restrict__ b_attn,
               const float* __restrict__ v_attn,
               const float* __restrict__ W_out, const float* __restrict__ b_out,
               float* __restrict__ pred_out, float* __restrict__ attn_out) {
  __shared__ __align__(16) float sPred[400];
  __shared__ __align__(16) float sIn[384];    // [x(128) | ctx(256)] GRU input
  __shared__ __align__(16) float sL1[256];
  __shared__ __align__(16) float sCat[512];   // [h(256) | ctx(256)] W_out input
  __shared__ __align__(16) float sSd[128];
  __shared__ __align__(16) float sScore[512];
  __shared__ __align__(16) float sRaw[400];
  __shared__ __align__(16) float sTmp[4096];  // float4[1024] partials
  __shared__ float sRed[16];

  float* sH   = sCat;
  float* sCtx = sCat + 256;

  const int b = blockIdx.x;
  const int tid = threadIdx.x;
  const int lane = tid & 63, wid = tid >> 6;
  const int l4 = tid & 3;

  // ---- init state
  for (int i = tid; i < 400; i += 1024) sPred[i] = 0.f;
  if (tid < 256) { sH[tid] = 0.f; sCtx[tid] = 0.f; sIn[128 + tid] = 0.f; }

  // ---- preload constants into registers
  float4 vq[8];
  #pragma unroll
  for (int i = 0; i < 8; ++i) vq[i] = *(const float4*)(v_attn + 4 * (l4 + 4 * i));

  float bP1 = 0.f, bR = 0.f, bZ = 0.f, bIN = 0.f, bHN = 0.f;
  if (tid < 256) {
    bP1 = b_p1[tid];
    bR  = b_ix[tid]       + b_ih[tid];
    bZ  = b_ix[256 + tid] + b_ih[256 + tid];
    bIN = b_ix[512 + tid];
    bHN = b_ih[512 + tid];
  }
  float bP2 = 0.f, bAt = 0.f;
  if (tid < 128) { bP2 = b_p2[tid]; bAt = b_attn[tid]; }
  float bOut = 0.f;
  if (tid < 400) bOut = b_out[tid];

  // ---- per-thread GEMV geometry (constant across steps)
  // P1: W_p1 [400x256]: 64 quads x 16 slices, KS=25
  const float* p1W = W_p1 + 4 * (tid & 63) + (size_t)((tid >> 6) * 25) * 256;
  const float* p1x = sPred + (tid >> 6) * 25;
  // P2: W_p2 [256x128]: 32 quads x 32 slices, KS=8
  const float* p2W = W_p2 + 4 * (tid & 31) + (size_t)((tid >> 5) * 8) * 128;
  const float* p2x = sL1 + (tid >> 5) * 8;
  // P6: W_dec [256x128]: same geometry, x = h
  const float* p6W = W_dec + 4 * (tid & 31) + (size_t)((tid >> 5) * 8) * 128;
  const float* p6x = sH + (tid >> 5) * 8;
  // GRU fused: 1024 virtual cols = [512 combined r/z | 256 i_n | 256 h_n]
  const float* gW = W_ix;
  const float* gx = sIn;
  const bool gAct = tid < 960;
  if (tid < 640) {
    int q = tid & 127, s = tid >> 7;
    int kbase = s * 128;
    if (kbase < 384) { gW = W_ix + (size_t)kbase * 768 + 4 * q; gx = sIn + kbase; }
    else             { gW = W_ih + (size_t)(kbase - 384) * 768 + 4 * q; gx = sH + (kbase - 384); }
  } else if (tid < 832) {
    int u = tid - 640, q = u & 63, s = u >> 6;
    gW = W_ix + (size_t)(s * 128) * 768 + 512 + 4 * q; gx = sIn + s * 128;
  } else if (tid < 960) {
    int u = tid - 832, q = u & 63, s = u >> 6;
    gW = W_ih + (size_t)(s * 128) * 768 + 512 + 4 * q; gx = sH + s * 128;
  }
  // P10: W_out [512x400]: 100 quads x 8 slices, KS=64 (800 active)
  const int q10 = tid % 100, s10 = tid / 100;
  const float* p10W = W_out + 4 * q10 + (size_t)(64 * s10) * 400;
  const float* p10x = sCat + 64 * s10;
  // P9: ctx: 64 e-quads x 16 tt-slices of 32
  const int e4i = tid & 63, sl9 = tid >> 6;
  const int t9a = sl9 * 32;
  const int t9b = (t9a + 32 < Tt) ? t9a + 32 : Tt;
  const float* fb9 = enc_feat + (size_t)b * Tt * Ee + 4 * e4i;

  __syncthreads();

  for (int t = 0; t < STEPS; ++t) {
    // ======== P1: l1 = relu(pred @ W_p1 + b_p1) ========
    { float4 a = dotq_db<25, 8>(p1W, 256, p1x); *(float4*)&sTmp[tid * 4] = a; }
    __syncthreads();
    if (tid < 256) {
      float v = bP1;
      #pragma unroll
      for (int s = 0; s < 16; ++s) v += sTmp[(s * 64 + (tid >> 2)) * 4 + (tid & 3)];
      sL1[tid] = fmaxf(v, 0.f);
    }
    __syncthreads();

    // ======== P2: x = relu(l1 @ W_p2 + b_p2) -> sIn[0:128] ========
    { float4 a = dotq_db<8, 8>(p2W, 128, p2x); *(float4*)&sTmp[tid * 4] = a; }
    __syncthreads();
    if (tid < 128) {
      float v = bP2;
      #pragma unroll
      for (int s = 0; s < 32; ++s) v += sTmp[(s * 32 + (tid >> 2)) * 4 + (tid & 3)];
      sIn[tid] = fmaxf(v, 0.f);
    }
    __syncthreads();

    // ======== GRU fused: all 6 GEMVs, one barrier, one combine ========
    if (gAct) { float4 a = dotq_db<128, 8>(gW, 768, gx); *(float4*)&sTmp[tid * 4] = a; }
    __syncthreads();
    if (tid < 256) {
      const int qr = tid >> 2, el = tid & 3;
      float cr = bR, cz = bZ, vin = bIN, vhn = bHN;
      #pragma unroll
      for (int s = 0; s < 5; ++s) cr += sTmp[(s * 128 + qr) * 4 + el];
      #pragma unroll
      for (int s = 0; s < 5; ++s) cz += sTmp[(s * 128 + 64 + qr) * 4 + el];
      #pragma unroll
      for (int s = 0; s < 3; ++s) vin += sTmp[(640 + s * 64 + qr) * 4 + el];
      #pragma unroll
      for (int s = 0; s < 2; ++s) vhn += sTmp[(832 + s * 64 + qr) * 4 + el];
      float r = sigmoid_acc(cr);
      float z = sigmoid_acc(cz);
      float n = tanh_acc(vin + r * vhn);
      sH[tid] = (1.f - z) * n + z * sH[tid];
    }
    __syncthreads();

    // ======== P6: s_dec = h @ W_dec + b_attn ========
    { float4 a = dotq_db<8, 8>(p6W, 128, p6x); *(float4*)&sTmp[tid * 4] = a; }
    __syncthreads();
    if (tid < 128) {
      float v = bAt;
      #pragma unroll
      for (int s = 0; s < 32; ++s) v += sTmp[(s * 32 + (tid >> 2)) * 4 + (tid & 3)];
      sSd[tid] = v;
    }
    __syncthreads();

    // ======== P7: scores[tt] = sum_a v[a]*tanh(enc_proj + s_dec) ========
    {
      float4 sdq[8];
      #pragma unroll
      for (int i = 0; i < 8; ++i) sdq[i] = *(const float4*)(sSd + 4 * (l4 + 4 * i));
      const int g = tid >> 2;
      #pragma unroll
      for (int p = 0; p < 2; ++p) {
        int tt = g + (p << 8);
        float acc = 0.f;
        if (tt < Tt) {
          const float* ep = enc_proj + ((size_t)b * Tt + tt) * Aa + 4 * l4;
          #pragma unroll
          for (int i = 0; i < 8; ++i) {
            f4v e4 = ntl4(ep + 16 * i);
            acc = fmaf(vq[i].x, tanh_fast(e4.x + sdq[i].x), acc);
            acc = fmaf(vq[i].y, tanh_fast(e4.y + sdq[i].y), acc);
            acc = fmaf(vq[i].z, tanh_fast(e4.z + sdq[i].z), acc);
            acc = fmaf(vq[i].w, tanh_fast(e4.w + sdq[i].w), acc);
          }
        }
        acc += __shfl_xor(acc, 1);
        acc += __shfl_xor(acc, 2);
        if (l4 == 0 && tt < Tt) sScore[tt] = acc;
      }
      __syncthreads();
    }

    // ======== P8: softmax over T; record attn ========
    {
      float val = (tid < Tt) ? sScore[tid] : -3.0e38f;
      float m = val;
      #pragma unroll
      for (int off = 32; off >= 1; off >>= 1) m = fmaxf(m, __shfl_xor(m, off));
      if (lane == 0) sRed[wid] = m;
      __syncthreads();
      float bm = sRed[0];
      #pragma unroll
      for (int w = 1; w < 16; ++w) bm = fmaxf(bm, sRed[w]);
      float e = (tid < Tt) ? __expf(val - bm) : 0.f;
      float ssum = e;
      #pragma unroll
      for (int off = 32; off >= 1; off >>= 1) ssum += __shfl_xor(ssum, off);
      __syncthreads();
      if (lane == 0) sRed[wid] = ssum;
      __syncthreads();
      float S = 0.f;
      #pragma unroll
      for (int w = 0; w < 16; ++w) S += sRed[w];
      if (tid < Tt) {
        float attn = e / S;
        sScore[tid] = attn;
        attn_out[((size_t)b * STEPS + t) * Tt + tid] = attn;
      }
      __syncthreads();
    }

    // ======== P9: ctx[e] = sum_tt attn[tt]*enc_feat[b,tt,e] ========
    {
      float accx = 0.f, accy = 0.f, accz = 0.f, accw = 0.f;
      #pragma unroll 8
      for (int tt = t9a; tt < t9b; ++tt) {
        float a = sScore[tt];
        f4v f = ntl4(fb9 + (size_t)tt * Ee);
        accx = fmaf(a, f.x, accx); accy = fmaf(a, f.y, accy);
        accz = fmaf(a, f.z, accz); accw = fmaf(a, f.w, accw);
      }
      float4 out = {accx, accy, accz, accw};
      *(float4*)&sTmp[tid * 4] = out;
      __syncthreads();
      if (tid < 256) {
        float v = 0.f;
        #pragma unroll
        for (int s = 0; s < 16; ++s) v += sTmp[(s * 64 + (tid >> 2)) * 4 + (tid & 3)];
        sCtx[tid] = v;
        sIn[128 + tid] = v;
      }
      __syncthreads();
    }

    // ======== P10: raw = [h,ctx] @ W_out + b_out ========
    if (tid < 800) { float4 a = dotq_db<64, 8>(p10W, 400, p10x); *(float4*)&sTmp[tid * 4] = a; }
    __syncthreads();
    if (tid < 400) {
      float v = bOut;
      #pragma unroll
      for (int s = 0; s < 8; ++s) v += sTmp[(s * 100 + (tid >> 2)) * 4 + (tid & 3)];
      sRaw[tid] = v;
    }
    __syncthreads();

    // ======== P11: pred = chunked softmax(raw, 5x80); record pred ========
    {
      if (wid < Rr) {
        int d0 = wid * 80 + lane;
        float v0 = sRaw[d0];
        float v1 = (lane < 16) ? sRaw[d0 + 64] : -3.0e38f;
        float m = fmaxf(v0, v1);
        #pragma unroll
        for (int off = 32; off >= 1; off >>= 1) m = fmaxf(m, __shfl_xor(m, off));
        float e0 = __expf(v0 - m);
        float e1 = (lane < 16) ? __expf(v1 - m) : 0.f;
        float s = e0 + e1;
        #pragma unroll
        for (int off = 32; off >= 1; off >>= 1) s += __shfl_xor(s, off);
        float inv = 1.0f / s;
        float p0 = e0 * inv;
        sPred[d0] = p0;
        pred_out[((size_t)b * STEPS + t) * Dd + d0] = p0;
        if (lane < 16) {
          float p1 = e1 * inv;
          sPred[d0 + 64] = p1;
          pred_out[((size_t)b * STEPS + t) * Dd + d0 + 64] = p1;
        }
      }
      __syncthreads();
    }
  }
}

// ---------------------------------------------------------------------------
extern "C" void kernel_launch(void* const* d_in, const int* in_sizes, int n_in,
                              void* d_out, int out_size, void* d_ws, size_t ws_size,
                              hipStream_t stream) {
  const float* enc_feat = (const float*)d_in[0];
  const float* W_p1  = (const float*)d_in[1];
  const float* b_p1  = (const float*)d_in[2];
  const float* W_p2  = (const float*)d_in[3];
  const float* b_p2  = (const float*)d_in[4];
  const float* W_ix  = (const float*)d_in[5];
  const float* W_ih  = (const float*)d_in[6];
  const float* b_ix  = (const float*)d_in[7];
  const float* b_ih  = (const float*)d_in[8];
  const float* W_dec = (const float*)d_in[9];
  const float* W_enc = (const float*)d_in[10];
  const float* b_attn= (const float*)d_in[11];
  const float* v_attn= (const float*)d_in[12];
  const float* W_out = (const float*)d_in[13];
  const float* b_out = (const float*)d_in[14];

  float* pred_out = (float*)d_out;                          // [64,500,400]
  float* attn_out = pred_out + (size_t)Bb * STEPS * Dd;     // [64,500,500]
  float* enc_proj = (float*)d_ws;                           // [64,500,128]

  k_encproj<<<dim3(Bb, 32), 512, 0, stream>>>(enc_feat, W_enc, enc_proj);
  k_decoder<<<Bb, 1024, 0, stream>>>(enc_feat, enc_proj,
                                     W_p1, b_p1, W_p2, b_p2,
                                     W_ix, W_ih, b_ix, b_ih,
                                     W_dec, b_attn, v_attn, W_out, b_out,
                                     pred_out, attn_out);
}